// Round 14
// baseline (259.624 us; speedup 1.0000x reference)
//
#include <hip/hip_runtime.h>
#include <stdint.h>

#define SEQ 2048
#define DM  1024
#define NH  16
#define HDIM 64
// total rows M = 4*2048 = 8192

typedef __bf16 bf16x8 __attribute__((ext_vector_type(8)));
typedef __bf16 bf16x4 __attribute__((ext_vector_type(4)));
typedef float  f32x4  __attribute__((ext_vector_type(4)));
typedef unsigned int u32x2 __attribute__((ext_vector_type(2)));
typedef unsigned int u32x4 __attribute__((ext_vector_type(4)));
typedef unsigned short u16x8 __attribute__((ext_vector_type(8)));

#define MFMA16(a,b,c) __builtin_amdgcn_mfma_f32_16x16x32_bf16((a),(b),(c),0,0,0)

// scale = (1/sqrt(64)) * log2(e), folded into Q projection; softmax uses exp2
#define QSCALE 0.18033688011112042f

// round-to-nearest-even fp32 -> bf16 bits
__device__ __forceinline__ unsigned short f2bf(float f) {
  unsigned int u = __float_as_uint(f);
  u += 0x7fffu + ((u >> 16) & 1u);
  return (unsigned short)(u >> 16);
}

// gfx950 lane swaps (both operands modified; deps via "+v" so the scheduler
// can still move them freely — no volatile).
__device__ __forceinline__ void plane32(unsigned int& a, unsigned int& b) {
  asm("v_permlane32_swap_b32 %0, %1" : "+v"(a), "+v"(b));
}
__device__ __forceinline__ void plane16(unsigned int& a, unsigned int& b) {
  asm("v_permlane16_swap_b32 %0, %1" : "+v"(a), "+v"(b));
}

// async global->LDS, 16 bytes per lane (dest = wave-uniform base + lane*16)
__device__ __forceinline__ void g2l16(const unsigned short* g, unsigned short* l) {
  __builtin_amdgcn_global_load_lds(
      (const __attribute__((address_space(1))) unsigned int*)g,
      (__attribute__((address_space(3))) unsigned int*)l, 16, 0, 0);
}

// ---------------- fused cast fp32 -> bf16 for X, Wq, Wk, Wv ----------------
// dest regions are contiguous in ws: [Xb | Wqb | Wkb | Wvb]
// r13: 8 elems/thread (2x float4 load, one 16B ushort8 store) — G13
// vectorization; all region sizes are multiples of 8 so no straddle.
// (measured: e2e 258.7 -> 254.2 µs)
__global__ __launch_bounds__(256) void cast_all(
    const float* __restrict__ x, const float* __restrict__ wq,
    const float* __restrict__ wk, const float* __restrict__ wv,
    unsigned short* __restrict__ out) {
  const int nX = 4 * SEQ * DM, nW = DM * DM;
  int i = (blockIdx.x * 256 + threadIdx.x) * 8;
  const float* src;
  int off;
  if (i < nX)                { src = x;  off = i; }
  else if (i < nX + nW)      { src = wq; off = i - nX; }
  else if (i < nX + 2 * nW)  { src = wk; off = i - nX - nW; }
  else                       { src = wv; off = i - nX - 2 * nW; }
  float4 v0 = *(const float4*)(src + off);
  float4 v1 = *(const float4*)(src + off + 4);
  u16x8 o;
  o[0] = f2bf(v0.x); o[1] = f2bf(v0.y); o[2] = f2bf(v0.z); o[3] = f2bf(v0.w);
  o[4] = f2bf(v1.x); o[5] = f2bf(v1.y); o[6] = f2bf(v1.z); o[7] = f2bf(v1.w);
  *(u16x8*)(out + i) = o;
}

// ---------------- QKV projection GEMM ----------------
// out[m][n] = sum_k X[m][k] * W[n][k] + bias[n]   (W given [n][k] row-major = B^T)
// grid (64 m-tiles, 24 combined z*n-tiles): all blocks sharing an X (A) tile
// have linear id == m (mod 8) -> same XCD -> X fetched ~once per XCD.
// r9 structure (session-best for qkv; r10's counted-vmcnt 3-buffer pipeline
// regressed to 103 µs via occupancy loss, r7's 1-barrier dbuf to 98 via
// stage/ds_read contention — both reverted):
// 2-barrier single-buffered staging, BK=64: half the per-step vmcnt drains of
// BK=32, 2x compute per stall. LDS 32 KB. Reads conflict-free via the 8-chunk
// XOR swizzle (r8 PMC: 6.3M conflict cycles -> 0): LDS slot (row,c) holds
// global chunk c^(row&7); staged by pre-swizzling the GLOBAL source (LDS dest
// linear for global_load_lds, rule #21); fragment read chunk (ks*4+l4)^(l15&7).
// z==0: Q (scaled by QSCALE) -> [b,h,s,hd]; z==1: K -> [b,h,s,hd];
// z==2: V -> [b,h,hd,s] via swapped MFMA operands (coalesced transposed stores).
__global__ __launch_bounds__(256) void qkv_gemm(
    const unsigned short* __restrict__ X,
    const unsigned short* __restrict__ W0, const unsigned short* __restrict__ W1,
    const unsigned short* __restrict__ W2,
    const float* __restrict__ b0, const float* __restrict__ b1, const float* __restrict__ b2,
    unsigned short* __restrict__ O0, unsigned short* __restrict__ O1,
    unsigned short* __restrict__ O2)
{
  const int z = blockIdx.y >> 3;
  const unsigned short* W = (z == 0) ? W0 : (z == 1) ? W1 : W2;
  const float* bias = (z == 0) ? b0 : (z == 1) ? b1 : b2;
  unsigned short* Out = (z == 0) ? O0 : (z == 1) ? O1 : O2;
  const float scale = (z == 0) ? QSCALE : 1.0f;
  const bool vtrans = (z == 2);

  __shared__ unsigned short As[128 * 64];   // 16 KB, [row][chunk^(row&7)]
  __shared__ unsigned short Bs[128 * 64];   // 16 KB

  const int t = threadIdx.x;
  const int lane = t & 63;
  const int l15 = lane & 15, l4 = lane >> 4;
  const int w = t >> 6;
  const int wm = (w >> 1) * 64;
  const int wn = (w & 1) * 64;
  const int bm = blockIdx.x * 128;
  const int bn = (blockIdx.y & 7) * 128;

  // staging: thread t covers LDS rows (t>>3)+j*32 (j=0..3), chunk t&7 (16 B);
  // global source chunk pre-swizzled (t&7)^((t>>3)&7) — constant across j,kt
  // since j*32 ≡ 0 (mod 8).
  const int scw = ((t & 7) ^ ((t >> 3) & 7)) * 8;
  const unsigned short* Ag = X + (size_t)(bm + (t >> 3)) * DM + scw;
  const unsigned short* Bg = W + (size_t)(bn + (t >> 3)) * DM + scw;

  f32x4 acc[4][4];
  #pragma unroll
  for (int mi = 0; mi < 4; mi++)
    #pragma unroll
    for (int ni = 0; ni < 4; ni++) acc[mi][ni] = (f32x4){0.f, 0.f, 0.f, 0.f};

  // fragment read chunk: (ks*4+l4) ^ (row&7), row = wm+mi*16+l15 -> l15&7
  const int swr = l15 & 7;
  int fo[2];
  #pragma unroll
  for (int ks = 0; ks < 2; ks++)
    fo[ks] = (((ks * 4 + l4) ^ swr) << 3);

  for (int kt = 0; kt < DM; kt += 64) {
    __syncthreads();
    #pragma unroll
    for (int j = 0; j < 4; j++) {
      g2l16(Ag + kt + (size_t)(j * 32) * DM, &As[j * 2048 + t * 8]);
      g2l16(Bg + kt + (size_t)(j * 32) * DM, &Bs[j * 2048 + t * 8]);
    }
    __syncthreads();

    bf16x8 af[4][2], bfr[4][2];
    #pragma unroll
    for (int mi = 0; mi < 4; mi++)
      #pragma unroll
      for (int ks = 0; ks < 2; ks++)
        af[mi][ks] = *(const bf16x8*)&As[(wm + mi * 16 + l15) * 64 + fo[ks]];
    #pragma unroll
    for (int ni = 0; ni < 4; ni++)
      #pragma unroll
      for (int ks = 0; ks < 2; ks++)
        bfr[ni][ks] = *(const bf16x8*)&Bs[(wn + ni * 16 + l15) * 64 + fo[ks]];
    if (!vtrans) {
      #pragma unroll
      for (int mi = 0; mi < 4; mi++)
        #pragma unroll
        for (int ni = 0; ni < 4; ni++) {
          acc[mi][ni] = MFMA16(af[mi][0], bfr[ni][0], acc[mi][ni]);
          acc[mi][ni] = MFMA16(af[mi][1], bfr[ni][1], acc[mi][ni]);
        }
    } else {
      #pragma unroll
      for (int mi = 0; mi < 4; mi++)
        #pragma unroll
        for (int ni = 0; ni < 4; ni++) {
          acc[mi][ni] = MFMA16(bfr[ni][0], af[mi][0], acc[mi][ni]);
          acc[mi][ni] = MFMA16(bfr[ni][1], af[mi][1], acc[mi][ni]);
        }
    }
  }

  if (!vtrans) {
    // C/D: col(l15)=n, row(l4*4+r)=m
    #pragma unroll
    for (int ni = 0; ni < 4; ni++) {
      int n = bn + wn + ni * 16 + l15;
      float bv = bias[n];
      int h = n >> 6, hd = n & 63;
      #pragma unroll
      for (int mi = 0; mi < 4; mi++) {
        #pragma unroll
        for (int r = 0; r < 4; r++) {
          int m = bm + wm + mi * 16 + l4 * 4 + r;
          float v = (acc[mi][ni][r] + bv) * scale;
          int b = m >> 11, s = m & 2047;
          Out[(size_t)(b * NH + h) * (SEQ * HDIM) + (size_t)s * HDIM + hd] = f2bf(v);
        }
      }
    }
  } else {
    // swapped: col(l15)=m(s), row(l4*4+r)=n(hd) -> coalesced stores along s
    #pragma unroll
    for (int ni = 0; ni < 4; ni++) {
      #pragma unroll
      for (int r = 0; r < 4; r++) {
        int n = bn + wn + ni * 16 + l4 * 4 + r;
        float bv = bias[n];
        int h = n >> 6, hd = n & 63;
        #pragma unroll
        for (int mi = 0; mi < 4; mi++) {
          int m = bm + wm + mi * 16 + l15;
          float v = acc[mi][ni][r] + bv;
          int b = m >> 11, s = m & 2047;
          Out[(size_t)(b * NH + h) * (SEQ * HDIM) + (size_t)hd * SEQ + s] = f2bf(v);
        }
      }
    }
  }
}

// ---------------- flash attention ----------------
// r5 structure (best measured: 86.7-87.4 µs across three runs). grid
// (64 b*h, 16 q-tiles): 4 waves x 32 q-rows (128 q/block) -> 1024 blocks =
// 4 blocks/CU = 4 waves/SIMD. K-tile = 64 keys, double-buffered LDS staged
// via global_load_lds with pre-swizzled global source (rule #21), ONE
// __syncthreads per tile; next tile's async loads issued BEFORE current
// tile's compute. S^T = K.Q^T (16x16x32); P stays in registers, relaid to
// the K=32 B-frag via permlane32/16 swaps. Row sums via ones-row MFMA.
// Softmax: fixed max=0, exp2 with log2e folded into Q scale. ctx written
// bf16 to workspace.
// Measured-refuted alternatives: K=16 PV (+18 µs: half-rate MFMA), LDS P
// round-trip (+7: bank conflicts + lgkm serialization), no-LDS direct-L2
// (+50: latency-bound at 2 waves/SIMD), vf-hoist reorder (+1: schedule
// perturbation).
__global__ __launch_bounds__(256) void attn_kernel(
    const unsigned short* __restrict__ Qg,
    const unsigned short* __restrict__ Kg,
    const unsigned short* __restrict__ Vg,
    unsigned short* __restrict__ ctxb)
{
  __shared__ unsigned short Klds[2][64 * 64];   // [buf][key][hd], swizzled (16 KB)
  __shared__ unsigned short Vlds[2][64 * 64];   // [buf][hd][key], swizzled (16 KB)

  const f32x4 ZERO4 = {0.f, 0.f, 0.f, 0.f};

  const int t = threadIdx.x;
  const int lane = t & 63;
  const int w = t >> 6;
  const int l15 = lane & 15, l4 = lane >> 4;
  const int bh = blockIdx.x;
  const int qt = blockIdx.y;

  const unsigned short* Q = Qg + (size_t)bh * SEQ * HDIM;
  const unsigned short* K = Kg + (size_t)bh * SEQ * HDIM;
  const unsigned short* V = Vg + (size_t)bh * HDIM * SEQ;  // [hd][s]

  const int q0 = qt * 128 + w * 32;

  // Q as B-operand fragments (loaded once from global): B[n=q][k=hd]
  bf16x8 qf[2][2];
  #pragma unroll
  for (int qi = 0; qi < 2; qi++)
    #pragma unroll
    for (int ks = 0; ks < 2; ks++)
      qf[qi][ks] = *(const bf16x8*)&Q[(size_t)(q0 + qi * 16 + l15) * HDIM + ks * 32 + l4 * 8];

  // ones A-fragment: row m=0 all ones -> D row 0 = column sums of B
  const __bf16 ob = (l15 == 0) ? (__bf16)1.0f : (__bf16)0.0f;
  const bf16x8 onesf = {ob, ob, ob, ob, ob, ob, ob, ob};

  f32x4 o[4][2];     // [hdi][qi]
  f32x4 psum[2];     // [qi]
  #pragma unroll
  for (int hdi = 0; hdi < 4; hdi++)
    #pragma unroll
    for (int qi = 0; qi < 2; qi++) o[hdi][qi] = ZERO4;
  #pragma unroll
  for (int qi = 0; qi < 2; qi++) psum[qi] = ZERO4;

  // --- staging: thread t <-> LDS bytes [t*16, t*16+16) = row r=t>>3, chunk t&7
  // (rows 0-31; second g2l16 call covers rows 32-63). Global source is
  // pre-swizzled so LDS content matches the old swizzled layout.
  const int r0 = t >> 3, c0 = t & 7;
  const int scw = (c0 ^ (r0 & 7)) * 8;               // (r0+32)&7 == r0&7
  const unsigned short* KgS = K + (size_t)r0 * HDIM + scw;
  const unsigned short* VgS = V + (size_t)r0 * SEQ + scw;

  // --- fragment LDS offsets (per-lane constants, shorts)
  const int sw = l15 & 7;
  int fboff[2];
  #pragma unroll
  for (int ks = 0; ks < 2; ks++)
    fboff[ks] = l15 * 64 + (((ks * 4 + l4) ^ sw) << 3);

  // prologue: stage tile 0 into buf 0
  g2l16(KgS, &Klds[0][t * 8]);
  g2l16(KgS + 32 * HDIM, &Klds[0][2048 + t * 8]);
  g2l16(VgS, &Vlds[0][t * 8]);
  g2l16(VgS + 32 * SEQ, &Vlds[0][2048 + t * 8]);
  __syncthreads();

  int cur = 0;
  for (int kt = 0; kt < SEQ; kt += 64) {
    // issue next tile's async loads into buf^1 (in flight during compute)
    if (kt + 64 < SEQ) {
      const unsigned short* kn = KgS + (size_t)(kt + 64) * HDIM;
      const unsigned short* vn = VgS + (kt + 64);
      g2l16(kn, &Klds[cur ^ 1][t * 8]);
      g2l16(kn + 32 * HDIM, &Klds[cur ^ 1][2048 + t * 8]);
      g2l16(vn, &Vlds[cur ^ 1][t * 8]);
      g2l16(vn + 32 * SEQ, &Vlds[cur ^ 1][2048 + t * 8]);
    }

    const unsigned short* Kc = Klds[cur];
    const unsigned short* Vc = Vlds[cur];

    // per 32-key slab-pair u: 2x (S^T = K.Q^T ; exp2 ; pack) -> permlane
    // relayout -> K=32 PV on in-register P
    #pragma unroll
    for (int u = 0; u < 2; u++) {
      unsigned int pw[2][4];  // [qi][word: A_s0, B_s0, A_s1, B_s1]
      #pragma unroll
      for (int half = 0; half < 2; half++) {
        const int slab = u * 2 + half;
        bf16x8 kf0 = *(const bf16x8*)(Kc + fboff[0] + slab * 1024);
        bf16x8 kf1 = *(const bf16x8*)(Kc + fboff[1] + slab * 1024);
        f32x4 sacc[2];
        __builtin_amdgcn_s_setprio(1);
        #pragma unroll
        for (int qi = 0; qi < 2; qi++) {
          sacc[qi] = MFMA16(kf0, qf[qi][0], ZERO4);
          sacc[qi] = MFMA16(kf1, qf[qi][1], sacc[qi]);
        }
        __builtin_amdgcn_s_setprio(0);
        #pragma unroll
        for (int qi = 0; qi < 2; qi++) {
          float p0 = __builtin_amdgcn_exp2f(sacc[qi][0]);
          float p1 = __builtin_amdgcn_exp2f(sacc[qi][1]);
          float p2 = __builtin_amdgcn_exp2f(sacc[qi][2]);
          float p3 = __builtin_amdgcn_exp2f(sacc[qi][3]);
          bf16x4 pb = {(__bf16)p0, (__bf16)p1, (__bf16)p2, (__bf16)p3};
          u32x2 pu = __builtin_bit_cast(u32x2, pb);
          pw[qi][half * 2 + 0] = pu.x;  // keys (4*l4, 4*l4+1) of this slab
          pw[qi][half * 2 + 1] = pu.y;  // keys (4*l4+2, 4*l4+3)
        }
      }

      // relayout: B-frag word w holds keys l4*8+2w, l4*8+2w+1 of the 32-key pair
      bf16x8 pfrag[2];
      #pragma unroll
      for (int qi = 0; qi < 2; qi++) {
        unsigned int a0 = pw[qi][0], b0 = pw[qi][1];
        unsigned int a1 = pw[qi][2], b1 = pw[qi][3];
        plane32(a0, a1);   // a0=[A0g0,A0g1,A1g0,A1g1] a1=[A0g2,A0g3,A1g2,A1g3]
        plane32(b0, b1);
        plane16(a0, a1);   // a0=word0, a1=word2
        plane16(b0, b1);   // b0=word1, b1=word3
        u32x4 uw = {a0, b0, a1, b1};
        pfrag[qi] = __builtin_bit_cast(bf16x8, uw);
      }

      bf16x8 vf[4];
      #pragma unroll
      for (int hdi = 0; hdi < 4; hdi++)
        vf[hdi] = *(const bf16x8*)(Vc + fboff[u] + hdi * 1024);

      __builtin_amdgcn_s_setprio(1);
      #pragma unroll
      for (int qi = 0; qi < 2; qi++)
        psum[qi] = MFMA16(onesf, pfrag[qi], psum[qi]);
      #pragma unroll
      for (int hdi = 0; hdi < 4; hdi++)
        #pragma unroll
        for (int qi = 0; qi < 2; qi++)
          o[hdi][qi] = MFMA16(vf[hdi], pfrag[qi], o[hdi][qi]);
      __builtin_amdgcn_s_setprio(0);
    }

    // all waves done reading buf[cur]; next tile's loads (into buf^1) drained
    __syncthreads();
    cur ^= 1;
  }

  // row sums live in D row 0 (lanes l4==0, reg 0, col=q). Broadcast per q=l15.
  float inv[2];
  #pragma unroll
  for (int qi = 0; qi < 2; qi++) inv[qi] = 1.0f / __shfl(psum[qi][0], l15);

  const int b = bh >> 4, h = bh & 15;
  #pragma unroll
  for (int hdi = 0; hdi < 4; hdi++)
    #pragma unroll
    for (int qi = 0; qi < 2; qi++) {
      int srow = q0 + qi * 16 + l15;
      f32x4 val = o[hdi][qi] * inv[qi];
      bf16x4 vk = {(__bf16)val[0], (__bf16)val[1], (__bf16)val[2], (__bf16)val[3]};
      *(bf16x4*)&ctxb[(size_t)(b * SEQ + srow) * DM + h * HDIM + hdi * 16 + l4 * 4] = vk;
    }
}

// ---------------- residual + LayerNorm (ctx in bf16, x fp32 -> out fp32) ----
// ~14 µs vs ~13.3 µs BW floor (80 MB @ 6.3 TB/s) — at roofline.
__global__ __launch_bounds__(256) void ln_kernel(const unsigned short* __restrict__ ctxb,
                                                 const float* __restrict__ x,
                                                 const float* __restrict__ gamma,
                                                 const float* __restrict__ beta,
                                                 float* __restrict__ out)
{
  const int row = blockIdx.x;
  const int t = threadIdx.x;
  const float* xr = x + (size_t)row * DM;
  float* orow = out + (size_t)row * DM;

  ushort4 cu = *(const ushort4*)(ctxb + (size_t)row * DM + t * 4);
  float4 xv = *(const float4*)(xr + t * 4);
  float v[4];
  v[0] = __uint_as_float((unsigned)cu.x << 16) + xv.x;
  v[1] = __uint_as_float((unsigned)cu.y << 16) + xv.y;
  v[2] = __uint_as_float((unsigned)cu.z << 16) + xv.z;
  v[3] = __uint_as_float((unsigned)cu.w << 16) + xv.w;
  float s = v[0] + v[1] + v[2] + v[3];
  float q = v[0] * v[0] + v[1] * v[1] + v[2] * v[2] + v[3] * v[3];
  #pragma unroll
  for (int off = 1; off < 64; off <<= 1) {
    s += __shfl_xor(s, off);
    q += __shfl_xor(q, off);
  }
  __shared__ float sh[8];
  int w = t >> 6, lane = t & 63;
  if (lane == 0) { sh[w] = s; sh[4 + w] = q; }
  __syncthreads();
  s = sh[0] + sh[1] + sh[2] + sh[3];
  q = sh[4] + sh[5] + sh[6] + sh[7];
  float mu = s * (1.0f / DM);
  float var = q * (1.0f / DM) - mu * mu;
  float rstd = rsqrtf(var + 1e-5f);
  float4 g = *(const float4*)(gamma + t * 4);
  float4 bt = *(const float4*)(beta + t * 4);
  float4 ov;
  ov.x = (v[0] - mu) * rstd * g.x + bt.x;
  ov.y = (v[1] - mu) * rstd * g.y + bt.y;
  ov.z = (v[2] - mu) * rstd * g.z + bt.z;
  ov.w = (v[3] - mu) * rstd * g.w + bt.w;
  *(float4*)(orow + t * 4) = ov;
}

extern "C" void kernel_launch(void* const* d_in, const int* in_sizes, int n_in,
                              void* d_out, int out_size, void* d_ws, size_t ws_size,
                              hipStream_t stream) {
  const float* x     = (const float*)d_in[0];
  const float* Wq    = (const float*)d_in[1];
  const float* bq    = (const float*)d_in[2];
  const float* Wk    = (const float*)d_in[3];
  const float* bk    = (const float*)d_in[4];
  const float* Wv    = (const float*)d_in[5];
  const float* bv    = (const float*)d_in[6];
  const float* gamma = (const float*)d_in[7];
  const float* beta  = (const float*)d_in[8];
  float* out = (float*)d_out;

  const int nX = 4 * SEQ * DM;  // 8388608
  const int nW = DM * DM;       // 1048576

  unsigned short* ws  = (unsigned short*)d_ws;
  unsigned short* Xb  = ws;            // also reused as bf16 ctx after qkv_gemm
  unsigned short* Wqb = Xb + nX;
  unsigned short* Wkb = Wqb + nW;
  unsigned short* Wvb = Wkb + nW;
  unsigned short* Qg  = Wvb + nW;
  unsigned short* Kg  = Qg + nX;
  unsigned short* Vg  = Kg + nX;   // total ~73.4 MB of workspace

  cast_all<<<(nX + 3 * nW) / 2048, 256, 0, stream>>>(x, Wq, Wk, Wv, Xb);
  qkv_gemm<<<dim3(64, 24), 256, 0, stream>>>(
      Xb, Wqb, Wkb, Wvb, bq, bk, bv, Qg, Kg, Vg);
  attn_kernel<<<dim3(4 * NH, SEQ / 128), 256, 0, stream>>>(Qg, Kg, Vg, Xb);
  ln_kernel<<<4 * SEQ, 256, 0, stream>>>(Xb, x, gamma, beta, out);
}

// Round 15
// 252.635 us; speedup vs baseline: 1.0277x; 1.0277x over previous
//
#include <hip/hip_runtime.h>
#include <stdint.h>

#define SEQ 2048
#define DM  1024
#define NH  16
#define HDIM 64
// total rows M = 4*2048 = 8192

typedef __bf16 bf16x8 __attribute__((ext_vector_type(8)));
typedef __bf16 bf16x4 __attribute__((ext_vector_type(4)));
typedef float  f32x4  __attribute__((ext_vector_type(4)));
typedef unsigned int u32x2 __attribute__((ext_vector_type(2)));
typedef unsigned int u32x4 __attribute__((ext_vector_type(4)));
typedef unsigned short u16x8 __attribute__((ext_vector_type(8)));

#define MFMA16(a,b,c) __builtin_amdgcn_mfma_f32_16x16x32_bf16((a),(b),(c),0,0,0)

// scale = (1/sqrt(64)) * log2(e), folded into Q projection; softmax uses exp2
#define QSCALE 0.18033688011112042f

// round-to-nearest-even fp32 -> bf16 bits
__device__ __forceinline__ unsigned short f2bf(float f) {
  unsigned int u = __float_as_uint(f);
  u += 0x7fffu + ((u >> 16) & 1u);
  return (unsigned short)(u >> 16);
}

// gfx950 lane swaps (both operands modified; deps via "+v" so the scheduler
// can still move them freely — no volatile).
__device__ __forceinline__ void plane32(unsigned int& a, unsigned int& b) {
  asm("v_permlane32_swap_b32 %0, %1" : "+v"(a), "+v"(b));
}
__device__ __forceinline__ void plane16(unsigned int& a, unsigned int& b) {
  asm("v_permlane16_swap_b32 %0, %1" : "+v"(a), "+v"(b));
}

// async global->LDS, 16 bytes per lane (dest = wave-uniform base + lane*16)
__device__ __forceinline__ void g2l16(const unsigned short* g, unsigned short* l) {
  __builtin_amdgcn_global_load_lds(
      (const __attribute__((address_space(1))) unsigned int*)g,
      (__attribute__((address_space(3))) unsigned int*)l, 16, 0, 0);
}

// ---------------- fused cast fp32 -> bf16 for X, Wq, Wk, Wv ----------------
// dest regions are contiguous in ws: [Xb | Wqb | Wkb | Wvb]
// r13: 8 elems/thread (2x float4 load, one 16B ushort8 store) — G13
// vectorization; all region sizes are multiples of 8 so no straddle.
// (measured: e2e 258.7 -> 254.2 µs)
__global__ __launch_bounds__(256) void cast_all(
    const float* __restrict__ x, const float* __restrict__ wq,
    const float* __restrict__ wk, const float* __restrict__ wv,
    unsigned short* __restrict__ out) {
  const int nX = 4 * SEQ * DM, nW = DM * DM;
  int i = (blockIdx.x * 256 + threadIdx.x) * 8;
  const float* src;
  int off;
  if (i < nX)                { src = x;  off = i; }
  else if (i < nX + nW)      { src = wq; off = i - nX; }
  else if (i < nX + 2 * nW)  { src = wk; off = i - nX - nW; }
  else                       { src = wv; off = i - nX - 2 * nW; }
  float4 v0 = *(const float4*)(src + off);
  float4 v1 = *(const float4*)(src + off + 4);
  u16x8 o;
  o[0] = f2bf(v0.x); o[1] = f2bf(v0.y); o[2] = f2bf(v0.z); o[3] = f2bf(v0.w);
  o[4] = f2bf(v1.x); o[5] = f2bf(v1.y); o[6] = f2bf(v1.z); o[7] = f2bf(v1.w);
  *(u16x8*)(out + i) = o;
}

// ---------------- QKV projection GEMM ----------------
// out[m][n] = sum_k X[m][k] * W[n][k] + bias[n]   (W given [n][k] row-major = B^T)
// grid (64 m-tiles, 24 combined z*n-tiles): all blocks sharing an X (A) tile
// have linear id == m (mod 8) -> same XCD -> X fetched ~once per XCD.
// r9 structure (session-best for qkv; r10's counted-vmcnt 3-buffer pipeline
// regressed to 103 µs via occupancy loss, r7's 1-barrier dbuf to 98 via
// stage/ds_read contention — both reverted):
// 2-barrier single-buffered staging, BK=64: half the per-step vmcnt drains of
// BK=32, 2x compute per stall. LDS 32 KB. Reads conflict-free via the 8-chunk
// XOR swizzle (r8 PMC: 6.3M conflict cycles -> 0): LDS slot (row,c) holds
// global chunk c^(row&7); staged by pre-swizzling the GLOBAL source (LDS dest
// linear for global_load_lds, rule #21); fragment read chunk (ks*4+l4)^(l15&7).
// z==0: Q (scaled by QSCALE) -> [b,h,s,hd]; z==1: K -> [b,h,s,hd];
// z==2: V -> [b,h,hd,s] via swapped MFMA operands (coalesced transposed stores).
__global__ __launch_bounds__(256) void qkv_gemm(
    const unsigned short* __restrict__ X,
    const unsigned short* __restrict__ W0, const unsigned short* __restrict__ W1,
    const unsigned short* __restrict__ W2,
    const float* __restrict__ b0, const float* __restrict__ b1, const float* __restrict__ b2,
    unsigned short* __restrict__ O0, unsigned short* __restrict__ O1,
    unsigned short* __restrict__ O2)
{
  const int z = blockIdx.y >> 3;
  const unsigned short* W = (z == 0) ? W0 : (z == 1) ? W1 : W2;
  const float* bias = (z == 0) ? b0 : (z == 1) ? b1 : b2;
  unsigned short* Out = (z == 0) ? O0 : (z == 1) ? O1 : O2;
  const float scale = (z == 0) ? QSCALE : 1.0f;
  const bool vtrans = (z == 2);

  __shared__ unsigned short As[128 * 64];   // 16 KB, [row][chunk^(row&7)]
  __shared__ unsigned short Bs[128 * 64];   // 16 KB

  const int t = threadIdx.x;
  const int lane = t & 63;
  const int l15 = lane & 15, l4 = lane >> 4;
  const int w = t >> 6;
  const int wm = (w >> 1) * 64;
  const int wn = (w & 1) * 64;
  const int bm = blockIdx.x * 128;
  const int bn = (blockIdx.y & 7) * 128;

  // staging: thread t covers LDS rows (t>>3)+j*32 (j=0..3), chunk t&7 (16 B);
  // global source chunk pre-swizzled (t&7)^((t>>3)&7) — constant across j,kt
  // since j*32 ≡ 0 (mod 8).
  const int scw = ((t & 7) ^ ((t >> 3) & 7)) * 8;
  const unsigned short* Ag = X + (size_t)(bm + (t >> 3)) * DM + scw;
  const unsigned short* Bg = W + (size_t)(bn + (t >> 3)) * DM + scw;

  f32x4 acc[4][4];
  #pragma unroll
  for (int mi = 0; mi < 4; mi++)
    #pragma unroll
    for (int ni = 0; ni < 4; ni++) acc[mi][ni] = (f32x4){0.f, 0.f, 0.f, 0.f};

  // fragment read chunk: (ks*4+l4) ^ (row&7), row = wm+mi*16+l15 -> l15&7
  const int swr = l15 & 7;
  int fo[2];
  #pragma unroll
  for (int ks = 0; ks < 2; ks++)
    fo[ks] = (((ks * 4 + l4) ^ swr) << 3);

  for (int kt = 0; kt < DM; kt += 64) {
    __syncthreads();
    #pragma unroll
    for (int j = 0; j < 4; j++) {
      g2l16(Ag + kt + (size_t)(j * 32) * DM, &As[j * 2048 + t * 8]);
      g2l16(Bg + kt + (size_t)(j * 32) * DM, &Bs[j * 2048 + t * 8]);
    }
    __syncthreads();

    bf16x8 af[4][2], bfr[4][2];
    #pragma unroll
    for (int mi = 0; mi < 4; mi++)
      #pragma unroll
      for (int ks = 0; ks < 2; ks++)
        af[mi][ks] = *(const bf16x8*)&As[(wm + mi * 16 + l15) * 64 + fo[ks]];
    #pragma unroll
    for (int ni = 0; ni < 4; ni++)
      #pragma unroll
      for (int ks = 0; ks < 2; ks++)
        bfr[ni][ks] = *(const bf16x8*)&Bs[(wn + ni * 16 + l15) * 64 + fo[ks]];
    if (!vtrans) {
      #pragma unroll
      for (int mi = 0; mi < 4; mi++)
        #pragma unroll
        for (int ni = 0; ni < 4; ni++) {
          acc[mi][ni] = MFMA16(af[mi][0], bfr[ni][0], acc[mi][ni]);
          acc[mi][ni] = MFMA16(af[mi][1], bfr[ni][1], acc[mi][ni]);
        }
    } else {
      #pragma unroll
      for (int mi = 0; mi < 4; mi++)
        #pragma unroll
        for (int ni = 0; ni < 4; ni++) {
          acc[mi][ni] = MFMA16(bfr[ni][0], af[mi][0], acc[mi][ni]);
          acc[mi][ni] = MFMA16(bfr[ni][1], af[mi][1], acc[mi][ni]);
        }
    }
  }

  if (!vtrans) {
    // C/D: col(l15)=n, row(l4*4+r)=m
    #pragma unroll
    for (int ni = 0; ni < 4; ni++) {
      int n = bn + wn + ni * 16 + l15;
      float bv = bias[n];
      int h = n >> 6, hd = n & 63;
      #pragma unroll
      for (int mi = 0; mi < 4; mi++) {
        #pragma unroll
        for (int r = 0; r < 4; r++) {
          int m = bm + wm + mi * 16 + l4 * 4 + r;
          float v = (acc[mi][ni][r] + bv) * scale;
          int b = m >> 11, s = m & 2047;
          Out[(size_t)(b * NH + h) * (SEQ * HDIM) + (size_t)s * HDIM + hd] = f2bf(v);
        }
      }
    }
  } else {
    // swapped: col(l15)=m(s), row(l4*4+r)=n(hd) -> coalesced stores along s
    #pragma unroll
    for (int ni = 0; ni < 4; ni++) {
      #pragma unroll
      for (int r = 0; r < 4; r++) {
        int n = bn + wn + ni * 16 + l4 * 4 + r;
        float bv = bias[n];
        int h = n >> 6, hd = n & 63;
        #pragma unroll
        for (int mi = 0; mi < 4; mi++) {
          int m = bm + wm + mi * 16 + l15;
          float v = acc[mi][ni][r] + bv;
          int b = m >> 11, s = m & 2047;
          Out[(size_t)(b * NH + h) * (SEQ * HDIM) + (size_t)hd * SEQ + s] = f2bf(v);
        }
      }
    }
  }
}

// ---------------- flash attention ----------------
// r5 structure (best measured: 86.7-88.0 µs across four runs). grid
// (64 b*h, 16 q-tiles): 4 waves x 32 q-rows (128 q/block) -> 1024 blocks =
// 4 blocks/CU = 4 waves/SIMD. K-tile = 64 keys, double-buffered LDS staged
// via global_load_lds with pre-swizzled global source (rule #21), ONE
// __syncthreads per tile; next tile's async loads issued BEFORE current
// tile's compute. S^T = K.Q^T (16x16x32); P stays in registers, relaid to
// the K=32 B-frag via permlane32/16 swaps. Row sums via ones-row MFMA.
// Softmax: fixed max=0, exp2 with log2e folded into Q scale. ctx written
// bf16 to workspace.
// Measured-refuted alternatives: K=16 PV (+18 µs: half-rate MFMA), LDS P
// round-trip (+7: bank conflicts + lgkm serialization), no-LDS direct-L2
// (+50: latency-bound at 2 waves/SIMD), vf-hoist reorder (+1: schedule
// perturbation).
__global__ __launch_bounds__(256) void attn_kernel(
    const unsigned short* __restrict__ Qg,
    const unsigned short* __restrict__ Kg,
    const unsigned short* __restrict__ Vg,
    unsigned short* __restrict__ ctxb)
{
  __shared__ unsigned short Klds[2][64 * 64];   // [buf][key][hd], swizzled (16 KB)
  __shared__ unsigned short Vlds[2][64 * 64];   // [buf][hd][key], swizzled (16 KB)

  const f32x4 ZERO4 = {0.f, 0.f, 0.f, 0.f};

  const int t = threadIdx.x;
  const int lane = t & 63;
  const int w = t >> 6;
  const int l15 = lane & 15, l4 = lane >> 4;
  const int bh = blockIdx.x;
  const int qt = blockIdx.y;

  const unsigned short* Q = Qg + (size_t)bh * SEQ * HDIM;
  const unsigned short* K = Kg + (size_t)bh * SEQ * HDIM;
  const unsigned short* V = Vg + (size_t)bh * HDIM * SEQ;  // [hd][s]

  const int q0 = qt * 128 + w * 32;

  // Q as B-operand fragments (loaded once from global): B[n=q][k=hd]
  bf16x8 qf[2][2];
  #pragma unroll
  for (int qi = 0; qi < 2; qi++)
    #pragma unroll
    for (int ks = 0; ks < 2; ks++)
      qf[qi][ks] = *(const bf16x8*)&Q[(size_t)(q0 + qi * 16 + l15) * HDIM + ks * 32 + l4 * 8];

  // ones A-fragment: row m=0 all ones -> D row 0 = column sums of B
  const __bf16 ob = (l15 == 0) ? (__bf16)1.0f : (__bf16)0.0f;
  const bf16x8 onesf = {ob, ob, ob, ob, ob, ob, ob, ob};

  f32x4 o[4][2];     // [hdi][qi]
  f32x4 psum[2];     // [qi]
  #pragma unroll
  for (int hdi = 0; hdi < 4; hdi++)
    #pragma unroll
    for (int qi = 0; qi < 2; qi++) o[hdi][qi] = ZERO4;
  #pragma unroll
  for (int qi = 0; qi < 2; qi++) psum[qi] = ZERO4;

  // --- staging: thread t <-> LDS bytes [t*16, t*16+16) = row r=t>>3, chunk t&7
  // (rows 0-31; second g2l16 call covers rows 32-63). Global source is
  // pre-swizzled so LDS content matches the old swizzled layout.
  const int r0 = t >> 3, c0 = t & 7;
  const int scw = (c0 ^ (r0 & 7)) * 8;               // (r0+32)&7 == r0&7
  const unsigned short* KgS = K + (size_t)r0 * HDIM + scw;
  const unsigned short* VgS = V + (size_t)r0 * SEQ + scw;

  // --- fragment LDS offsets (per-lane constants, shorts)
  const int sw = l15 & 7;
  int fboff[2];
  #pragma unroll
  for (int ks = 0; ks < 2; ks++)
    fboff[ks] = l15 * 64 + (((ks * 4 + l4) ^ sw) << 3);

  // prologue: stage tile 0 into buf 0
  g2l16(KgS, &Klds[0][t * 8]);
  g2l16(KgS + 32 * HDIM, &Klds[0][2048 + t * 8]);
  g2l16(VgS, &Vlds[0][t * 8]);
  g2l16(VgS + 32 * SEQ, &Vlds[0][2048 + t * 8]);
  __syncthreads();

  int cur = 0;
  for (int kt = 0; kt < SEQ; kt += 64) {
    // issue next tile's async loads into buf^1 (in flight during compute)
    if (kt + 64 < SEQ) {
      const unsigned short* kn = KgS + (size_t)(kt + 64) * HDIM;
      const unsigned short* vn = VgS + (kt + 64);
      g2l16(kn, &Klds[cur ^ 1][t * 8]);
      g2l16(kn + 32 * HDIM, &Klds[cur ^ 1][2048 + t * 8]);
      g2l16(vn, &Vlds[cur ^ 1][t * 8]);
      g2l16(vn + 32 * SEQ, &Vlds[cur ^ 1][2048 + t * 8]);
    }

    const unsigned short* Kc = Klds[cur];
    const unsigned short* Vc = Vlds[cur];

    // per 32-key slab-pair u: 2x (S^T = K.Q^T ; exp2 ; pack) -> permlane
    // relayout -> K=32 PV on in-register P
    #pragma unroll
    for (int u = 0; u < 2; u++) {
      unsigned int pw[2][4];  // [qi][word: A_s0, B_s0, A_s1, B_s1]
      #pragma unroll
      for (int half = 0; half < 2; half++) {
        const int slab = u * 2 + half;
        bf16x8 kf0 = *(const bf16x8*)(Kc + fboff[0] + slab * 1024);
        bf16x8 kf1 = *(const bf16x8*)(Kc + fboff[1] + slab * 1024);
        f32x4 sacc[2];
        __builtin_amdgcn_s_setprio(1);
        #pragma unroll
        for (int qi = 0; qi < 2; qi++) {
          sacc[qi] = MFMA16(kf0, qf[qi][0], ZERO4);
          sacc[qi] = MFMA16(kf1, qf[qi][1], sacc[qi]);
        }
        __builtin_amdgcn_s_setprio(0);
        #pragma unroll
        for (int qi = 0; qi < 2; qi++) {
          float p0 = __builtin_amdgcn_exp2f(sacc[qi][0]);
          float p1 = __builtin_amdgcn_exp2f(sacc[qi][1]);
          float p2 = __builtin_amdgcn_exp2f(sacc[qi][2]);
          float p3 = __builtin_amdgcn_exp2f(sacc[qi][3]);
          bf16x4 pb = {(__bf16)p0, (__bf16)p1, (__bf16)p2, (__bf16)p3};
          u32x2 pu = __builtin_bit_cast(u32x2, pb);
          pw[qi][half * 2 + 0] = pu.x;  // keys (4*l4, 4*l4+1) of this slab
          pw[qi][half * 2 + 1] = pu.y;  // keys (4*l4+2, 4*l4+3)
        }
      }

      // relayout: B-frag word w holds keys l4*8+2w, l4*8+2w+1 of the 32-key pair
      bf16x8 pfrag[2];
      #pragma unroll
      for (int qi = 0; qi < 2; qi++) {
        unsigned int a0 = pw[qi][0], b0 = pw[qi][1];
        unsigned int a1 = pw[qi][2], b1 = pw[qi][3];
        plane32(a0, a1);   // a0=[A0g0,A0g1,A1g0,A1g1] a1=[A0g2,A0g3,A1g2,A1g3]
        plane32(b0, b1);
        plane16(a0, a1);   // a0=word0, a1=word2
        plane16(b0, b1);   // b0=word1, b1=word3
        u32x4 uw = {a0, b0, a1, b1};
        pfrag[qi] = __builtin_bit_cast(bf16x8, uw);
      }

      bf16x8 vf[4];
      #pragma unroll
      for (int hdi = 0; hdi < 4; hdi++)
        vf[hdi] = *(const bf16x8*)(Vc + fboff[u] + hdi * 1024);

      __builtin_amdgcn_s_setprio(1);
      #pragma unroll
      for (int qi = 0; qi < 2; qi++)
        psum[qi] = MFMA16(onesf, pfrag[qi], psum[qi]);
      #pragma unroll
      for (int hdi = 0; hdi < 4; hdi++)
        #pragma unroll
        for (int qi = 0; qi < 2; qi++)
          o[hdi][qi] = MFMA16(vf[hdi], pfrag[qi], o[hdi][qi]);
      __builtin_amdgcn_s_setprio(0);
    }

    // all waves done reading buf[cur]; next tile's loads (into buf^1) drained
    __syncthreads();
    cur ^= 1;
  }

  // row sums live in D row 0 (lanes l4==0, reg 0, col=q). Broadcast per q=l15.
  float inv[2];
  #pragma unroll
  for (int qi = 0; qi < 2; qi++) inv[qi] = 1.0f / __shfl(psum[qi][0], l15);

  const int b = bh >> 4, h = bh & 15;
  #pragma unroll
  for (int hdi = 0; hdi < 4; hdi++)
    #pragma unroll
    for (int qi = 0; qi < 2; qi++) {
      int srow = q0 + qi * 16 + l15;
      f32x4 val = o[hdi][qi] * inv[qi];
      bf16x4 vk = {(__bf16)val[0], (__bf16)val[1], (__bf16)val[2], (__bf16)val[3]};
      *(bf16x4*)&ctxb[(size_t)(b * SEQ + srow) * DM + h * HDIM + hdi * 16 + l4 * 4] = vk;
    }
}

// ---------------- residual + LayerNorm (ctx in bf16, x fp32 -> out fp32) ----
// r15: wave-per-row. One 64-lane wave owns one 1024-elem row: lane covers
// elems (j*64+lane)*4, j=0..3 — each float4 load/store instruction spans 256
// consecutive floats (fully coalesced). Reduction is 6 __shfl_xor steps;
// NO LDS, NO __syncthreads (removes the cross-wave combine + 2 barriers of
// the old 256-thr/row version). 4 rows/block -> grid 8192 -> 2048 (G11).
__global__ __launch_bounds__(256) void ln_kernel(const unsigned short* __restrict__ ctxb,
                                                 const float* __restrict__ x,
                                                 const float* __restrict__ gamma,
                                                 const float* __restrict__ beta,
                                                 float* __restrict__ out)
{
  const int w = threadIdx.x >> 6, lane = threadIdx.x & 63;
  const int row = blockIdx.x * 4 + w;
  const unsigned short* crow = ctxb + (size_t)row * DM;
  const float* xr = x + (size_t)row * DM;
  float* orow = out + (size_t)row * DM;

  float v[16];
  float s = 0.f, q = 0.f;
  #pragma unroll
  for (int j = 0; j < 4; j++) {
    const int idx = (j * 64 + lane) * 4;
    ushort4 cu = *(const ushort4*)(crow + idx);
    float4 xv = *(const float4*)(xr + idx);
    float a0 = __uint_as_float((unsigned)cu.x << 16) + xv.x;
    float a1 = __uint_as_float((unsigned)cu.y << 16) + xv.y;
    float a2 = __uint_as_float((unsigned)cu.z << 16) + xv.z;
    float a3 = __uint_as_float((unsigned)cu.w << 16) + xv.w;
    v[j * 4 + 0] = a0; v[j * 4 + 1] = a1; v[j * 4 + 2] = a2; v[j * 4 + 3] = a3;
    s += (a0 + a1) + (a2 + a3);
    q += (a0 * a0 + a1 * a1) + (a2 * a2 + a3 * a3);
  }
  #pragma unroll
  for (int off = 1; off < 64; off <<= 1) {
    s += __shfl_xor(s, off);
    q += __shfl_xor(q, off);
  }
  float mu = s * (1.0f / DM);
  float var = q * (1.0f / DM) - mu * mu;
  float rstd = rsqrtf(var + 1e-5f);
  #pragma unroll
  for (int j = 0; j < 4; j++) {
    const int idx = (j * 64 + lane) * 4;
    float4 g = *(const float4*)(gamma + idx);
    float4 bt = *(const float4*)(beta + idx);
    float4 ov;
    ov.x = (v[j * 4 + 0] - mu) * rstd * g.x + bt.x;
    ov.y = (v[j * 4 + 1] - mu) * rstd * g.y + bt.y;
    ov.z = (v[j * 4 + 2] - mu) * rstd * g.z + bt.z;
    ov.w = (v[j * 4 + 3] - mu) * rstd * g.w + bt.w;
    *(float4*)(orow + idx) = ov;
  }
}

extern "C" void kernel_launch(void* const* d_in, const int* in_sizes, int n_in,
                              void* d_out, int out_size, void* d_ws, size_t ws_size,
                              hipStream_t stream) {
  const float* x     = (const float*)d_in[0];
  const float* Wq    = (const float*)d_in[1];
  const float* bq    = (const float*)d_in[2];
  const float* Wk    = (const float*)d_in[3];
  const float* bk    = (const float*)d_in[4];
  const float* Wv    = (const float*)d_in[5];
  const float* bv    = (const float*)d_in[6];
  const float* gamma = (const float*)d_in[7];
  const float* beta  = (const float*)d_in[8];
  float* out = (float*)d_out;

  const int nX = 4 * SEQ * DM;  // 8388608
  const int nW = DM * DM;       // 1048576

  unsigned short* ws  = (unsigned short*)d_ws;
  unsigned short* Xb  = ws;            // also reused as bf16 ctx after qkv_gemm
  unsigned short* Wqb = Xb + nX;
  unsigned short* Wkb = Wqb + nW;
  unsigned short* Wvb = Wkb + nW;
  unsigned short* Qg  = Wvb + nW;
  unsigned short* Kg  = Qg + nX;
  unsigned short* Vg  = Kg + nX;   // total ~73.4 MB of workspace

  cast_all<<<(nX + 3 * nW) / 2048, 256, 0, stream>>>(x, Wq, Wk, Wv, Xb);
  qkv_gemm<<<dim3(64, 24), 256, 0, stream>>>(
      Xb, Wqb, Wkb, Wvb, bq, bk, bv, Qg, Kg, Vg);
  attn_kernel<<<dim3(4 * NH, SEQ / 128), 256, 0, stream>>>(Qg, Kg, Vg, Xb);
  ln_kernel<<<4 * SEQ / 4, 256, 0, stream>>>(Xb, x, gamma, beta, out);
}